// Round 12
// baseline (177.563 us; speedup 1.0000x reference)
//
#include <hip/hip_runtime.h>
#include <hip/hip_bf16.h>
#include <stdint.h>

typedef float f32x4 __attribute__((ext_vector_type(4)));
typedef short short8 __attribute__((ext_vector_type(8)));
typedef __bf16 bf16x8 __attribute__((ext_vector_type(8)));

#define D_MODEL 512
#define MAX_LEN 1024
#define M_TOTAL 65536

static __device__ __forceinline__ short f2bf(float f) {
  union { __hip_bfloat16 h; short s; } u;
  u.h = __float2bfloat16(f);
  return u.s;
}

static __device__ __forceinline__ float bf2f(unsigned short u) {
  union { unsigned int i; float f; } v;
  v.i = ((unsigned int)u) << 16;
  return v.f;
}

static __device__ __forceinline__ bf16x8 as_bf16x8(short8 s) {
  union { short8 s; bf16x8 b; } u;
  u.s = s;
  return u.b;
}

// async global->LDS, 16B per lane. LDS dest must be wave-uniform base + lane*16.
static __device__ __forceinline__ void gload_lds16(const void* g, void* l) {
  __builtin_amdgcn_global_load_lds(
      (const __attribute__((address_space(1))) uint32_t*)(uintptr_t)g,
      (__attribute__((address_space(3))) uint32_t*)(uint32_t)(uintptr_t)l,
      16, 0, 0);
}

static __device__ __forceinline__ void mfma_bf16(f32x4& c, short8 a, short8 b) {
  asm("v_mfma_f32_16x16x32_bf16 %0, %1, %2, %0" : "+v"(c) : "v"(a), "v"(b));
}

// ---------------- prep: W [1024][512] f32 -> WtopT / WbotT [512][512] bf16 ([n][k]) ----
__global__ __launch_bounds__(256) void prep_w_kernel(const float* __restrict__ W,
                                                     short* __restrict__ WtT,
                                                     short* __restrict__ WbT) {
  __shared__ float tile[64][65];
  const int t = threadIdx.x;
  const int nt = blockIdx.x * 64;   // n tile in [0,512)
  const int kt = blockIdx.y * 64;   // k tile in [0,1024)
  const int c = t & 63;
  const int r0 = t >> 6;
#pragma unroll
  for (int r = r0; r < 64; r += 4)
    tile[r][c] = W[(size_t)(kt + r) * D_MODEL + nt + c];
  __syncthreads();
  short* dst = (kt < D_MODEL) ? WtT : WbT;
  const int kb = kt & (D_MODEL - 1);
#pragma unroll
  for (int n = r0; n < 64; n += 4)
    dst[(size_t)(nt + n) * D_MODEL + kb + c] = f2bf(tile[c][n]);
}

// ---------------- prep: encoding [1024][512] f32 -> bf16 (row-major) -------------------
__global__ __launch_bounds__(256) void prep_enc_kernel(const float* __restrict__ enc,
                                                       short* __restrict__ encb) {
  const int i = (blockIdx.x * 256 + threadIdx.x) * 4;
  float4 v = *reinterpret_cast<const float4*>(enc + i);
  short4 r = make_short4(f2bf(v.x), f2bf(v.y), f2bf(v.z), f2bf(v.w));
  *reinterpret_cast<short4*>(encb + i) = r;
}

// ---------------- GEMM1: encW[1024][512] = enc_bf16 @ WtopT^T (fp32 out) ---------------
__global__ __launch_bounds__(256) void gemm_encw_kernel(const short* __restrict__ A,
                                                        const short* __restrict__ BT,
                                                        float* __restrict__ C) {
  __shared__ short As[128 * 32];
  __shared__ short Bs[128 * 32];
  const int t = threadIdx.x;
  const int lane = t & 63;
  const int wave = t >> 6;
  const int wm = wave >> 1, wn = wave & 1;
  const int m0 = blockIdx.y * 128, n0 = blockIdx.x * 128;
  const int koff = (t & 3) * 8;
  const int rr = t >> 2;
  const int l15 = lane & 15, lk = (lane >> 4) * 8;
  f32x4 acc[4][4] = {};
  for (int kt = 0; kt < D_MODEL; kt += 32) {
    __syncthreads();
    gload_lds16(A + (size_t)(m0 + rr) * D_MODEL + kt + koff, (char*)As + t * 16);
    gload_lds16(A + (size_t)(m0 + 64 + rr) * D_MODEL + kt + koff, (char*)As + 4096 + t * 16);
    gload_lds16(BT + (size_t)(n0 + rr) * D_MODEL + kt + koff, (char*)Bs + t * 16);
    gload_lds16(BT + (size_t)(n0 + 64 + rr) * D_MODEL + kt + koff, (char*)Bs + 4096 + t * 16);
    __syncthreads();
    short8 af[4], bfr[4];
#pragma unroll
    for (int mi = 0; mi < 4; ++mi)
      af[mi] = *reinterpret_cast<const short8*>(&As[(wm * 64 + mi * 16 + l15) * 32 + lk]);
#pragma unroll
    for (int ni = 0; ni < 4; ++ni)
      bfr[ni] = *reinterpret_cast<const short8*>(&Bs[(wn * 64 + ni * 16 + l15) * 32 + lk]);
#pragma unroll
    for (int mi = 0; mi < 4; ++mi)
#pragma unroll
      for (int ni = 0; ni < 4; ++ni)
        mfma_bf16(acc[mi][ni], af[mi], bfr[ni]);
  }
#pragma unroll
  for (int mi = 0; mi < 4; ++mi)
#pragma unroll
    for (int r = 0; r < 4; ++r) {
      const int row = m0 + wm * 64 + mi * 16 + (lane >> 4) * 4 + r;
#pragma unroll
      for (int ni = 0; ni < 4; ++ni) {
        const int col = n0 + wn * 64 + ni * 16 + l15;
        C[(size_t)row * D_MODEL + col] = acc[mi][ni][r];
      }
    }
}

// ---------------- gather: posW[65536][512] bf16 = encW[dfn] + encW[dfa] + bias ---------
// 2048 blocks x 256t; 32 rows/block, 8 threads/row, 64 cols/thread.
// encW (2MB) is L2-resident; 8-lane groups read 2KB-contiguous row slices.
__global__ __launch_bounds__(256) void gather_pos_kernel(
    const float* __restrict__ encW, const int* __restrict__ dfn,
    const int* __restrict__ dfa, const float* __restrict__ bias,
    unsigned short* __restrict__ posW) {
  const int t = threadIdx.x;
  const int row = blockIdx.x * 32 + (t >> 3);
  const int c0 = (t & 7) * 64;
  const float* e1 = encW + (size_t)dfn[row] * D_MODEL + c0;
  const float* e2 = encW + (size_t)dfa[row] * D_MODEL + c0;
  const float* bi = bias + c0;
  unsigned short* dst = posW + (size_t)row * D_MODEL + c0;
#pragma unroll
  for (int c = 0; c < 8; ++c) {
    f32x4 a0 = *reinterpret_cast<const f32x4*>(e1 + c * 8);
    f32x4 a1 = *reinterpret_cast<const f32x4*>(e1 + c * 8 + 4);
    f32x4 b0 = *reinterpret_cast<const f32x4*>(e2 + c * 8);
    f32x4 b1 = *reinterpret_cast<const f32x4*>(e2 + c * 8 + 4);
    f32x4 s0 = *reinterpret_cast<const f32x4*>(bi + c * 8);
    f32x4 s1 = *reinterpret_cast<const f32x4*>(bi + c * 8 + 4);
    short8 h;
    h[0] = f2bf(a0[0] + b0[0] + s0[0]); h[1] = f2bf(a0[1] + b0[1] + s0[1]);
    h[2] = f2bf(a0[2] + b0[2] + s0[2]); h[3] = f2bf(a0[3] + b0[3] + s0[3]);
    h[4] = f2bf(a1[0] + b1[0] + s1[0]); h[5] = f2bf(a1[1] + b1[1] + s1[1]);
    h[6] = f2bf(a1[2] + b1[2] + s1[2]); h[7] = f2bf(a1[3] + b1[3] + s1[3]);
    *reinterpret_cast<short8*>(dst + c * 8) = h;
  }
}

// ---------------- GEMM2: out = latent @ WbotT^T + pos ---------------------------------
// m97-order K-loop: BM=BN=128, BK=64, 4 waves (2x2), single-buffered LDS,
// barrier / stage(12x gload_lds) / barrier / compute. 48KB LDS -> 3 blocks/CU.
// A staged RAW F32 [128][64] (32KB, 256B rows = 16 slots, swizzle s^=(r&15));
// B bf16 [128][64] (16KB, 128B rows = 8 slots, swizzle s^=(r&7)).
// Both swizzles applied via pre-swizzled GLOBAL source (rule #21); frag reads
// XOR-bijective over each 16-lane group -> 2 lanes/bank-quad = conflict-free.
// cvt f32->bf16 in the compute phase (VALU, overlaps MFMA pipe).
// Epilogue: use_pos ? contiguous bf16 posW read : legacy fused gather.
__global__ __launch_bounds__(256, 3) void gemm_main_kernel(
    const float* __restrict__ latent,   // [65536][512] f32
    const short* __restrict__ BT,       // WbotT [512][512] bf16 ([n][k])
    const float* __restrict__ encW,     // [1024][512] f32 (legacy path)
    const int* __restrict__ dfn,
    const int* __restrict__ dfa,
    const float* __restrict__ bias,
    const unsigned short* __restrict__ posW,  // [65536][512] bf16
    int use_pos,
    float* __restrict__ out) {          // [65536][512] f32
  __shared__ alignas(16) float Af[128 * 64];   // 32 KB
  __shared__ alignas(16) short Bs[128 * 64];   // 16 KB
  const int t = threadIdx.x;
  const int lane = t & 63;
  const int wave = t >> 6;
  const int wm = wave >> 1, wn = wave & 1;

  // XCD-chunked mapping: xcd = bid&7 owns m-panels [xcd*64, xcd*64+64);
  // 4 n-blocks of each m-panel consecutive -> same-XCD L2 reuse of A.
  const int bid = blockIdx.x;
  const int slot = bid >> 3;
  const int mblk = (bid & 7) * 64 + (slot >> 2);
  const int nblk = slot & 3;
  const int m0 = mblk * 128, n0 = nblk * 128;

  const int l15 = lane & 15;
  const int lsl = lane >> 4;   // k sub-slot 0..3

  // A staging: pass p (0..7): LDS byte p*4096 + t*16 = (row p*16 + (t>>4), slot t&15)
  // pre-swizzled source: f32 col = ((t&15) ^ ((t>>4)&15)) * 4
  const int arow = t >> 4;
  const float* aSrc = latent + (size_t)(m0 + arow) * D_MODEL + ((t & 15) ^ arow) * 4;
  // B staging: pass p (0..3): LDS byte p*4096 + t*16 = (row p*32 + (t>>3), slot t&7)
  // pre-swizzled source: bf16 col = ((t&7) ^ ((t>>3)&7)) * 8
  const int brow = t >> 3;
  const short* bSrc = BT + (size_t)(n0 + brow) * D_MODEL + ((t & 7) ^ (brow & 7)) * 8;

  f32x4 acc[4][4] = {};

  for (int kt = 0; kt < D_MODEL; kt += 64) {
    __syncthreads();   // everyone done reading prev tile
#pragma unroll
    for (int p = 0; p < 8; ++p)
      gload_lds16(aSrc + (size_t)p * 16 * D_MODEL + kt, (char*)Af + p * 4096 + t * 16);
#pragma unroll
    for (int p = 0; p < 4; ++p)
      gload_lds16(bSrc + (size_t)p * 32 * D_MODEL + kt, (char*)Bs + p * 4096 + t * 16);
    __syncthreads();   // vmcnt(0)+barrier: staged tile visible
#pragma unroll
    for (int kk = 0; kk < 2; ++kk) {
      bf16x8 af[4], bfv[4];
#pragma unroll
      for (int mi = 0; mi < 4; ++mi) {
        const int r = wm * 64 + mi * 16 + l15;
        const int s0 = (kk * 8 + lsl * 2) ^ (r & 15);
        const int s1 = (kk * 8 + lsl * 2 + 1) ^ (r & 15);
        f32x4 v0 = *reinterpret_cast<const f32x4*>((const char*)Af + r * 256 + s0 * 16);
        f32x4 v1 = *reinterpret_cast<const f32x4*>((const char*)Af + r * 256 + s1 * 16);
        short8 h;
        h[0] = f2bf(v0[0]); h[1] = f2bf(v0[1]); h[2] = f2bf(v0[2]); h[3] = f2bf(v0[3]);
        h[4] = f2bf(v1[0]); h[5] = f2bf(v1[1]); h[6] = f2bf(v1[2]); h[7] = f2bf(v1[3]);
        af[mi] = as_bf16x8(h);
      }
#pragma unroll
      for (int ni = 0; ni < 4; ++ni) {
        const int r = wn * 64 + ni * 16 + l15;
        const int s = (kk * 4 + lsl) ^ (r & 7);
        bfv[ni] = as_bf16x8(
            *reinterpret_cast<const short8*>((const char*)Bs + r * 128 + s * 16));
      }
#pragma unroll
      for (int mi = 0; mi < 4; ++mi)
#pragma unroll
        for (int ni = 0; ni < 4; ++ni)
          acc[mi][ni] = __builtin_amdgcn_mfma_f32_16x16x32_bf16(
              af[mi], bfv[ni], acc[mi][ni], 0, 0, 0);
    }
  }

  if (use_pos) {
    // contiguous, row-aligned bf16 pos read (no gather, no bias)
#pragma unroll
    for (int mi = 0; mi < 4; ++mi) {
#pragma unroll
      for (int r = 0; r < 4; ++r) {
        const int row = m0 + wm * 64 + mi * 16 + lsl * 4 + r;
        const size_t ro = (size_t)row * D_MODEL;
#pragma unroll
        for (int ni = 0; ni < 4; ++ni) {
          const int col = n0 + wn * 64 + ni * 16 + l15;
          out[ro + col] = acc[mi][ni][r] + bf2f(posW[ro + col]);
        }
      }
    }
  } else {
    // legacy fused gather epilogue
#pragma unroll
    for (int mi = 0; mi < 4; ++mi) {
#pragma unroll
      for (int r = 0; r < 4; ++r) {
        const int row = m0 + wm * 64 + mi * 16 + lsl * 4 + r;
        const int d1 = dfn[row];
        const int d2 = dfa[row];
        const float* e1 = encW + (size_t)d1 * D_MODEL;
        const float* e2 = encW + (size_t)d2 * D_MODEL;
        const size_t ro = (size_t)row * D_MODEL;
#pragma unroll
        for (int ni = 0; ni < 4; ++ni) {
          const int col = n0 + wn * 64 + ni * 16 + l15;
          out[ro + col] = acc[mi][ni][r] + e1[col] + e2[col] + bias[col];
        }
      }
    }
  }
}

extern "C" void kernel_launch(void* const* d_in, const int* in_sizes, int n_in,
                              void* d_out, int out_size, void* d_ws, size_t ws_size,
                              hipStream_t stream) {
  const int* dfn = (const int*)d_in[0];
  const int* dfa = (const int*)d_in[1];
  const float* latent = (const float*)d_in[2];
  const float* enc = (const float*)d_in[3];
  const float* W = (const float*)d_in[4];
  const float* bias = (const float*)d_in[5];
  float* out = (float*)d_out;

  // workspace layout
  char* ws = (char*)d_ws;
  short* WtT  = (short*)(ws);                       // 512KB  [512][512] bf16
  short* WbT  = (short*)(ws + 512 * 1024);          // 512KB  [512][512] bf16
  short* encb = (short*)(ws + 1024 * 1024);         // 1MB    [1024][512] bf16
  float* encW = (float*)(ws + 2 * 1024 * 1024);     // 2MB    [1024][512] f32
  const size_t POSW_OFF = 4u * 1024 * 1024;
  unsigned short* posW = (unsigned short*)(ws + POSW_OFF);  // 64MB [65536][512] bf16
  const size_t need = POSW_OFF + (size_t)M_TOTAL * D_MODEL * 2;
  const int use_pos = (ws_size >= need) ? 1 : 0;

  hipLaunchKernelGGL(prep_w_kernel, dim3(8, 16), dim3(256), 0, stream, W, WtT, WbT);
  hipLaunchKernelGGL(prep_enc_kernel, dim3(512), dim3(256), 0, stream, enc, encb);
  hipLaunchKernelGGL(gemm_encw_kernel, dim3(4, 8), dim3(256), 0, stream, encb, WtT, encW);
  if (use_pos)
    hipLaunchKernelGGL(gather_pos_kernel, dim3(2048), dim3(256), 0, stream,
                       encW, dfn, dfa, bias, posW);
  hipLaunchKernelGGL(gemm_main_kernel, dim3(2048), dim3(256), 0, stream,
                     latent, WbT, encW, dfn, dfa, bias, posW, use_pos, out);
}

// Round 15
// 167.418 us; speedup vs baseline: 1.0606x; 1.0606x over previous
//
#include <hip/hip_runtime.h>
#include <hip/hip_bf16.h>
#include <stdint.h>

typedef float f32x4 __attribute__((ext_vector_type(4)));
typedef short short8 __attribute__((ext_vector_type(8)));
typedef __bf16 bf16x8 __attribute__((ext_vector_type(8)));

#define D_MODEL 512
#define MAX_LEN 1024
#define M_TOTAL 65536

static __device__ __forceinline__ short f2bf(float f) {
  union { __hip_bfloat16 h; short s; } u;
  u.h = __float2bfloat16(f);
  return u.s;
}

static __device__ __forceinline__ bf16x8 as_bf16x8(short8 s) {
  union { short8 s; bf16x8 b; } u;
  u.s = s;
  return u.b;
}

// async global->LDS, 16B per lane. LDS dest must be wave-uniform base + lane*16.
static __device__ __forceinline__ void gload_lds16(const void* g, void* l) {
  __builtin_amdgcn_global_load_lds(
      (const __attribute__((address_space(1))) uint32_t*)(uintptr_t)g,
      (__attribute__((address_space(3))) uint32_t*)(uint32_t)(uintptr_t)l,
      16, 0, 0);
}

static __device__ __forceinline__ void mfma_bf16(f32x4& c, short8 a, short8 b) {
  asm("v_mfma_f32_16x16x32_bf16 %0, %1, %2, %0" : "+v"(c) : "v"(a), "v"(b));
}

// ---------------- prep: W [1024][512] f32 -> WtopT / WbotT [512][512] bf16 ([n][k]) ----
__global__ __launch_bounds__(256) void prep_w_kernel(const float* __restrict__ W,
                                                     short* __restrict__ WtT,
                                                     short* __restrict__ WbT) {
  __shared__ float tile[64][65];
  const int t = threadIdx.x;
  const int nt = blockIdx.x * 64;   // n tile in [0,512)
  const int kt = blockIdx.y * 64;   // k tile in [0,1024)
  const int c = t & 63;
  const int r0 = t >> 6;
#pragma unroll
  for (int r = r0; r < 64; r += 4)
    tile[r][c] = W[(size_t)(kt + r) * D_MODEL + nt + c];
  __syncthreads();
  short* dst = (kt < D_MODEL) ? WtT : WbT;
  const int kb = kt & (D_MODEL - 1);
#pragma unroll
  for (int n = r0; n < 64; n += 4)
    dst[(size_t)(nt + n) * D_MODEL + kb + c] = f2bf(tile[c][n]);
}

// ---------------- prep: encoding [1024][512] f32 -> bf16 (row-major) -------------------
__global__ __launch_bounds__(256) void prep_enc_kernel(const float* __restrict__ enc,
                                                       short* __restrict__ encb) {
  const int i = (blockIdx.x * 256 + threadIdx.x) * 4;
  float4 v = *reinterpret_cast<const float4*>(enc + i);
  short4 r = make_short4(f2bf(v.x), f2bf(v.y), f2bf(v.z), f2bf(v.w));
  *reinterpret_cast<short4*>(encb + i) = r;
}

// ---------------- GEMM1: encW[1024][512] = enc_bf16 @ WtopT^T (fp32 out) ---------------
__global__ __launch_bounds__(256) void gemm_encw_kernel(const short* __restrict__ A,
                                                        const short* __restrict__ BT,
                                                        float* __restrict__ C) {
  __shared__ short As[128 * 32];
  __shared__ short Bs[128 * 32];
  const int t = threadIdx.x;
  const int lane = t & 63;
  const int wave = t >> 6;
  const int wm = wave >> 1, wn = wave & 1;
  const int m0 = blockIdx.y * 128, n0 = blockIdx.x * 128;
  const int koff = (t & 3) * 8;
  const int rr = t >> 2;
  const int l15 = lane & 15, lk = (lane >> 4) * 8;
  f32x4 acc[4][4] = {};
  for (int kt = 0; kt < D_MODEL; kt += 32) {
    __syncthreads();
    gload_lds16(A + (size_t)(m0 + rr) * D_MODEL + kt + koff, (char*)As + t * 16);
    gload_lds16(A + (size_t)(m0 + 64 + rr) * D_MODEL + kt + koff, (char*)As + 4096 + t * 16);
    gload_lds16(BT + (size_t)(n0 + rr) * D_MODEL + kt + koff, (char*)Bs + t * 16);
    gload_lds16(BT + (size_t)(n0 + 64 + rr) * D_MODEL + kt + koff, (char*)Bs + 4096 + t * 16);
    __syncthreads();
    short8 af[4], bfr[4];
#pragma unroll
    for (int mi = 0; mi < 4; ++mi)
      af[mi] = *reinterpret_cast<const short8*>(&As[(wm * 64 + mi * 16 + l15) * 32 + lk]);
#pragma unroll
    for (int ni = 0; ni < 4; ++ni)
      bfr[ni] = *reinterpret_cast<const short8*>(&Bs[(wn * 64 + ni * 16 + l15) * 32 + lk]);
#pragma unroll
    for (int mi = 0; mi < 4; ++mi)
#pragma unroll
      for (int ni = 0; ni < 4; ++ni)
        mfma_bf16(acc[mi][ni], af[mi], bfr[ni]);
  }
#pragma unroll
  for (int mi = 0; mi < 4; ++mi)
#pragma unroll
    for (int r = 0; r < 4; ++r) {
      const int row = m0 + wm * 64 + mi * 16 + (lane >> 4) * 4 + r;
#pragma unroll
      for (int ni = 0; ni < 4; ++ni) {
        const int col = n0 + wn * 64 + ni * 16 + l15;
        C[(size_t)row * D_MODEL + col] = acc[mi][ni][r];
      }
    }
}

// ---------------- GEMM2: out = latent @ WbotT^T + encW[dfn] + encW[dfa] + b ------------
// A-DIRECT + proven 2-barrier cadence (deterministic in r11/r12):
//   per K-step: barrier -> STAGE_B (4x gload_lds, 16KB) -> barrier(vmcnt drain) ->
//   COMPUTE (A-fragments straight from global in MFMA layout, f32->bf16 cvt in-reg,
//   32 MFMA). A never touches LDS; its plain loads are not gated by barriers.
// B single-buffered [128][64] bf16 (16KB LDS), zero-conflict XOR swizzle via
// pre-swizzled global source (rule #21). 3 blocks/CU interleave their drains.
__global__ __launch_bounds__(256, 3) void gemm_main_kernel(
    const float* __restrict__ latent,   // [65536][512] f32
    const short* __restrict__ BT,       // WbotT [512][512] bf16 ([n][k])
    const float* __restrict__ encW,     // [1024][512] f32
    const int* __restrict__ dfn,
    const int* __restrict__ dfa,
    const float* __restrict__ bias,     // [512]
    float* __restrict__ out) {          // [65536][512] f32
  __shared__ alignas(16) short Bs[128 * 64];   // 16 KB
  const int t = threadIdx.x;
  const int lane = t & 63;
  const int wave = t >> 6;          // 0..3, owns rows [wave*32, wave*32+32)

  // XCD-chunked mapping: xcd = bid&7 owns m-panels [xcd*64, xcd*64+64);
  // 4 n-blocks of each m-panel consecutive -> same-XCD L2 reuse of A.
  const int bid = blockIdx.x;
  const int slot = bid >> 3;
  const int mblk = (bid & 7) * 64 + (slot >> 2);
  const int nblk = slot & 3;
  const int m0 = mblk * 128, n0 = nblk * 128;

  const int l15 = lane & 15;
  const int lsl = lane >> 4;   // k sub-slot 0..3

  // B staging: pass p (0..3): LDS byte p*4096 + t*16 = (row p*32 + (t>>3), slot t&7)
  // pre-swizzled source: bf16 col = ((t&7) ^ ((t>>3)&7)) * 8
  const int brow = t >> 3;
  const short* bSrc = BT + (size_t)(n0 + brow) * D_MODEL + ((t & 7) ^ (brow & 7)) * 8;

  // A fragment bases (MFMA layout, lane = (lsl<<4)|l15): rows wave*32 + mi*16 + l15
  const float* aF0 = latent + (size_t)(m0 + wave * 32 + l15) * D_MODEL + lsl * 8;
  const float* aF1 = aF0 + (size_t)16 * D_MODEL;

  f32x4 acc[2][8] = {};

#define STAGE_B(KO)                                                         \
  do {                                                                      \
    _Pragma("unroll") for (int p = 0; p < 4; ++p)                           \
        gload_lds16(bSrc + (size_t)p * 32 * D_MODEL + (KO),                 \
                    (char*)Bs + p * 4096 + t * 16);                         \
  } while (0)
#define COMPUTE(KT)                                                         \
  do {                                                                      \
    _Pragma("unroll") for (int kk = 0; kk < 2; ++kk) {                      \
      bf16x8 af[2], bfv[8];                                                 \
      {                                                                     \
        f32x4 v0 = *reinterpret_cast<const f32x4*>(aF0 + (KT) + kk * 32);   \
        f32x4 v1 = *reinterpret_cast<const f32x4*>(aF0 + (KT) + kk * 32 + 4);\
        short8 h;                                                           \
        h[0] = f2bf(v0[0]); h[1] = f2bf(v0[1]); h[2] = f2bf(v0[2]); h[3] = f2bf(v0[3]); \
        h[4] = f2bf(v1[0]); h[5] = f2bf(v1[1]); h[6] = f2bf(v1[2]); h[7] = f2bf(v1[3]); \
        af[0] = as_bf16x8(h);                                               \
        v0 = *reinterpret_cast<const f32x4*>(aF1 + (KT) + kk * 32);         \
        v1 = *reinterpret_cast<const f32x4*>(aF1 + (KT) + kk * 32 + 4);     \
        h[0] = f2bf(v0[0]); h[1] = f2bf(v0[1]); h[2] = f2bf(v0[2]); h[3] = f2bf(v0[3]); \
        h[4] = f2bf(v1[0]); h[5] = f2bf(v1[1]); h[6] = f2bf(v1[2]); h[7] = f2bf(v1[3]); \
        af[1] = as_bf16x8(h);                                               \
      }                                                                     \
      _Pragma("unroll") for (int ni = 0; ni < 8; ++ni) {                    \
        const int r = ni * 16 + l15;                                        \
        const int s = (kk * 4 + lsl) ^ (r & 7);                             \
        bfv[ni] = as_bf16x8(                                                \
            *reinterpret_cast<const short8*>((const char*)Bs + r * 128 + s * 16)); \
      }                                                                     \
      _Pragma("unroll") for (int mi = 0; mi < 2; ++mi)                      \
          _Pragma("unroll") for (int ni = 0; ni < 8; ++ni)                  \
              acc[mi][ni] = __builtin_amdgcn_mfma_f32_16x16x32_bf16(        \
                  af[mi], bfv[ni], acc[mi][ni], 0, 0, 0);                   \
    }                                                                       \
  } while (0)

  // main loop: 8 K-steps, proven 2-barrier cadence, single-buffered B
#pragma unroll
  for (int tt = 0; tt < 8; ++tt) {
    const int kt = tt * 64;
    __syncthreads();   // all waves done reading Bs from previous step
    STAGE_B(kt);
    __syncthreads();   // vmcnt(0) drain: staged B visible to all waves
    COMPUTE(kt);
  }

  // epilogue: fused gather of encW rows (2 MB, L2/L3-resident) + bias
#pragma unroll
  for (int mi = 0; mi < 2; ++mi) {
#pragma unroll
    for (int r = 0; r < 4; ++r) {
      const int row = m0 + wave * 32 + mi * 16 + lsl * 4 + r;
      const int d1 = dfn[row];
      const int d2 = dfa[row];
      const float* e1 = encW + (size_t)d1 * D_MODEL;
      const float* e2 = encW + (size_t)d2 * D_MODEL;
      const size_t ro = (size_t)row * D_MODEL;
#pragma unroll
      for (int ni = 0; ni < 8; ++ni) {
        const int col = n0 + ni * 16 + l15;
        out[ro + col] = acc[mi][ni][r] + e1[col] + e2[col] + bias[col];
      }
    }
  }
#undef STAGE_B
#undef COMPUTE
}

extern "C" void kernel_launch(void* const* d_in, const int* in_sizes, int n_in,
                              void* d_out, int out_size, void* d_ws, size_t ws_size,
                              hipStream_t stream) {
  const int* dfn = (const int*)d_in[0];
  const int* dfa = (const int*)d_in[1];
  const float* latent = (const float*)d_in[2];
  const float* enc = (const float*)d_in[3];
  const float* W = (const float*)d_in[4];
  const float* bias = (const float*)d_in[5];
  float* out = (float*)d_out;

  // workspace layout (4 MB total)
  char* ws = (char*)d_ws;
  short* WtT  = (short*)(ws);                       // 512KB  [512][512] bf16
  short* WbT  = (short*)(ws + 512 * 1024);          // 512KB  [512][512] bf16
  short* encb = (short*)(ws + 1024 * 1024);         // 1MB    [1024][512] bf16
  float* encW = (float*)(ws + 2 * 1024 * 1024);     // 2MB    [1024][512] f32

  hipLaunchKernelGGL(prep_w_kernel, dim3(8, 16), dim3(256), 0, stream, W, WtT, WbT);
  hipLaunchKernelGGL(prep_enc_kernel, dim3(512), dim3(256), 0, stream, enc, encb);
  hipLaunchKernelGGL(gemm_encw_kernel, dim3(4, 8), dim3(256), 0, stream, encb, WtT, encW);
  hipLaunchKernelGGL(gemm_main_kernel, dim3(2048), dim3(256), 0, stream,
                     latent, WbT, encW, dfn, dfa, bias, out);
}

// Round 16
// 120.599 us; speedup vs baseline: 1.4723x; 1.3882x over previous
//
#include <hip/hip_runtime.h>
#include <hip/hip_bf16.h>
#include <stdint.h>

typedef float f32x4 __attribute__((ext_vector_type(4)));
typedef short short8 __attribute__((ext_vector_type(8)));
typedef __bf16 bf16x8 __attribute__((ext_vector_type(8)));

#define D_MODEL 512
#define MAX_LEN 1024
#define M_TOTAL 65536

static __device__ __forceinline__ short f2bf(float f) {
  union { __hip_bfloat16 h; short s; } u;
  u.h = __float2bfloat16(f);
  return u.s;
}

static __device__ __forceinline__ bf16x8 as_bf16x8(short8 s) {
  union { short8 s; bf16x8 b; } u;
  u.s = s;
  return u.b;
}

// async global->LDS, 16B per lane. LDS dest must be wave-uniform base + lane*16.
static __device__ __forceinline__ void gload_lds16(const void* g, void* l) {
  __builtin_amdgcn_global_load_lds(
      (const __attribute__((address_space(1))) uint32_t*)(uintptr_t)g,
      (__attribute__((address_space(3))) uint32_t*)(uint32_t)(uintptr_t)l,
      16, 0, 0);
}

static __device__ __forceinline__ void mfma_bf16(f32x4& c, short8 a, short8 b) {
  asm("v_mfma_f32_16x16x32_bf16 %0, %1, %2, %0" : "+v"(c) : "v"(a), "v"(b));
}

// ---------------- prep: W [1024][512] f32 -> WtopT / WbotT [512][512] bf16 ([n][k]) ----
__global__ __launch_bounds__(256) void prep_w_kernel(const float* __restrict__ W,
                                                     short* __restrict__ WtT,
                                                     short* __restrict__ WbT) {
  __shared__ float tile[64][65];
  const int t = threadIdx.x;
  const int nt = blockIdx.x * 64;   // n tile in [0,512)
  const int kt = blockIdx.y * 64;   // k tile in [0,1024)
  const int c = t & 63;
  const int r0 = t >> 6;
#pragma unroll
  for (int r = r0; r < 64; r += 4)
    tile[r][c] = W[(size_t)(kt + r) * D_MODEL + nt + c];
  __syncthreads();
  short* dst = (kt < D_MODEL) ? WtT : WbT;
  const int kb = kt & (D_MODEL - 1);
#pragma unroll
  for (int n = r0; n < 64; n += 4)
    dst[(size_t)(nt + n) * D_MODEL + kb + c] = f2bf(tile[c][n]);
}

// ---------------- prep: encoding [1024][512] f32 -> bf16 (row-major) -------------------
__global__ __launch_bounds__(256) void prep_enc_kernel(const float* __restrict__ enc,
                                                       short* __restrict__ encb) {
  const int i = (blockIdx.x * 256 + threadIdx.x) * 4;
  float4 v = *reinterpret_cast<const float4*>(enc + i);
  short4 r = make_short4(f2bf(v.x), f2bf(v.y), f2bf(v.z), f2bf(v.w));
  *reinterpret_cast<short4*>(encb + i) = r;
}

// ---------------- GEMM1: encW[1024][512] = enc_bf16 @ WtopT^T (fp32 out) ---------------
__global__ __launch_bounds__(256) void gemm_encw_kernel(const short* __restrict__ A,
                                                        const short* __restrict__ BT,
                                                        float* __restrict__ C) {
  __shared__ short As[128 * 32];
  __shared__ short Bs[128 * 32];
  const int t = threadIdx.x;
  const int lane = t & 63;
  const int wave = t >> 6;
  const int wm = wave >> 1, wn = wave & 1;
  const int m0 = blockIdx.y * 128, n0 = blockIdx.x * 128;
  const int koff = (t & 3) * 8;
  const int rr = t >> 2;
  const int l15 = lane & 15, lk = (lane >> 4) * 8;
  f32x4 acc[4][4] = {};
  for (int kt = 0; kt < D_MODEL; kt += 32) {
    __syncthreads();
    gload_lds16(A + (size_t)(m0 + rr) * D_MODEL + kt + koff, (char*)As + t * 16);
    gload_lds16(A + (size_t)(m0 + 64 + rr) * D_MODEL + kt + koff, (char*)As + 4096 + t * 16);
    gload_lds16(BT + (size_t)(n0 + rr) * D_MODEL + kt + koff, (char*)Bs + t * 16);
    gload_lds16(BT + (size_t)(n0 + 64 + rr) * D_MODEL + kt + koff, (char*)Bs + 4096 + t * 16);
    __syncthreads();
    short8 af[4], bfr[4];
#pragma unroll
    for (int mi = 0; mi < 4; ++mi)
      af[mi] = *reinterpret_cast<const short8*>(&As[(wm * 64 + mi * 16 + l15) * 32 + lk]);
#pragma unroll
    for (int ni = 0; ni < 4; ++ni)
      bfr[ni] = *reinterpret_cast<const short8*>(&Bs[(wn * 64 + ni * 16 + l15) * 32 + lk]);
#pragma unroll
    for (int mi = 0; mi < 4; ++mi)
#pragma unroll
      for (int ni = 0; ni < 4; ++ni)
        mfma_bf16(acc[mi][ni], af[mi], bfr[ni]);
  }
#pragma unroll
  for (int mi = 0; mi < 4; ++mi)
#pragma unroll
    for (int r = 0; r < 4; ++r) {
      const int row = m0 + wm * 64 + mi * 16 + (lane >> 4) * 4 + r;
#pragma unroll
      for (int ni = 0; ni < 4; ++ni) {
        const int col = n0 + wn * 64 + ni * 16 + l15;
        C[(size_t)row * D_MODEL + col] = acc[mi][ni][r];
      }
    }
}

// ---------------- GEMM2: out = latent @ WbotT^T + encW[dfn] + encW[dfa] + b ------------
// Issue-early double-buffered K-loop (T3-minimum recipe, explicit drain):
//   per step: STAGE(t+1 -> other buffer) -> COMPUTE(t) ->
//             asm s_waitcnt vmcnt(0) lgkmcnt(0); sched_barrier(0); __syncthreads().
// Prefetched gloads get the whole compute phase to land; drain residual is small.
// Full vmcnt(0) drain EVERY step => deterministic (no counted-vmcnt hazard).
// BK=32; A f32 [128][32] (16KB/buf, 8x16B slots, swizzle s^=(r&7));
// B bf16 [128][32] (8KB/buf, 4x16B slots, swizzle s^=((r>>1)&3)); 48KB total, 3 blk/CU.
// Staging/read formulas are r11's correctness-verified ones (pre-swizzled source).
// Epilogue: fused LDS-coalesced gather (per-wave 4KB region, coalesced f32x4 loads).
__global__ __launch_bounds__(256, 3) void gemm_main_kernel(
    const float* __restrict__ latent,   // [65536][512] f32
    const short* __restrict__ BT,       // WbotT [512][512] bf16 ([n][k])
    const float* __restrict__ encW,     // [1024][512] f32
    const int* __restrict__ dfn,
    const int* __restrict__ dfa,
    const float* __restrict__ bias,     // [512]
    float* __restrict__ out) {          // [65536][512] f32
  __shared__ alignas(16) float Af0[128 * 32];   // 16 KB
  __shared__ alignas(16) float Af1[128 * 32];   // 16 KB
  __shared__ alignas(16) short Bs0[128 * 32];   // 8 KB
  __shared__ alignas(16) short Bs1[128 * 32];   // 8 KB
  const int t = threadIdx.x;
  const int lane = t & 63;
  const int wave = t >> 6;
  const int wm = wave >> 1, wn = wave & 1;

  // XCD-chunked mapping: xcd = bid&7 owns m-panels [xcd*64, xcd*64+64);
  // 4 n-blocks of each m-panel consecutive -> same-XCD L2 reuse of A.
  const int bid = blockIdx.x;
  const int slot = bid >> 3;
  const int mblk = (bid & 7) * 64 + (slot >> 2);
  const int nblk = slot & 3;
  const int m0 = mblk * 128, n0 = nblk * 128;

  const int l15 = lane & 15;
  const int lsl = lane >> 4;   // k sub-slot 0..3

  // A staging: pass p (0..3): LDS byte p*4096 + t*16 = (row p*32 + (t>>3), slot t&7)
  // pre-swizzled source: f32 col = ((t&7) ^ ((t>>3)&7)) * 4   [r11-verified]
  const int arow = t >> 3;
  const float* aSrc = latent + (size_t)(m0 + arow) * D_MODEL + ((t & 7) ^ (arow & 7)) * 4;
  // B staging: pass p (0..1): LDS byte p*4096 + t*16 = (row p*64 + (t>>2), slot t&3)
  // pre-swizzled source: bf16 col = ((t&3) ^ ((t>>3)&3)) * 8  [r11-verified]
  const int brow = t >> 2;
  const short* bSrc = BT + (size_t)(n0 + brow) * D_MODEL + ((t & 3) ^ ((t >> 3) & 3)) * 8;

  f32x4 acc[4][4] = {};

#define STAGE(KO, ADST, BDST)                                               \
  do {                                                                      \
    _Pragma("unroll") for (int p = 0; p < 4; ++p)                           \
        gload_lds16(aSrc + (size_t)p * 32 * D_MODEL + (KO),                 \
                    (char*)(ADST) + p * 4096 + t * 16);                     \
    _Pragma("unroll") for (int p = 0; p < 2; ++p)                           \
        gload_lds16(bSrc + (size_t)p * 64 * D_MODEL + (KO),                 \
                    (char*)(BDST) + p * 4096 + t * 16);                     \
  } while (0)
#define COMPUTE(ASRC, BSRC)                                                 \
  do {                                                                      \
    bf16x8 af[4], bfv[4];                                                   \
    _Pragma("unroll") for (int mi = 0; mi < 4; ++mi) {                      \
      const int r = wm * 64 + mi * 16 + l15;                                \
      const int s0 = (2 * lsl) ^ (r & 7);                                   \
      const int s1 = (2 * lsl + 1) ^ (r & 7);                               \
      f32x4 v0 = *reinterpret_cast<const f32x4*>((const char*)(ASRC) + r * 128 + s0 * 16); \
      f32x4 v1 = *reinterpret_cast<const f32x4*>((const char*)(ASRC) + r * 128 + s1 * 16); \
      short8 h;                                                             \
      h[0] = f2bf(v0[0]); h[1] = f2bf(v0[1]); h[2] = f2bf(v0[2]); h[3] = f2bf(v0[3]); \
      h[4] = f2bf(v1[0]); h[5] = f2bf(v1[1]); h[6] = f2bf(v1[2]); h[7] = f2bf(v1[3]); \
      af[mi] = as_bf16x8(h);                                                \
    }                                                                       \
    _Pragma("unroll") for (int ni = 0; ni < 4; ++ni) {                      \
      const int r = wn * 64 + ni * 16 + l15;                                \
      const int s = lsl ^ ((r >> 1) & 3);                                   \
      bfv[ni] = as_bf16x8(                                                  \
          *reinterpret_cast<const short8*>((const char*)(BSRC) + r * 64 + s * 16)); \
    }                                                                       \
    _Pragma("unroll") for (int mi = 0; mi < 4; ++mi)                        \
        _Pragma("unroll") for (int ni = 0; ni < 4; ++ni)                    \
            acc[mi][ni] = __builtin_amdgcn_mfma_f32_16x16x32_bf16(          \
                af[mi], bfv[ni], acc[mi][ni], 0, 0, 0);                     \
  } while (0)
#define DRAIN_BARRIER()                                                     \
  do {                                                                      \
    asm volatile("s_waitcnt vmcnt(0) lgkmcnt(0)" ::: "memory");             \
    __builtin_amdgcn_sched_barrier(0);                                      \
    __syncthreads();                                                        \
  } while (0)

  // prologue: tile 0 into buffer 0, full drain
  STAGE(0, Af0, Bs0);
  DRAIN_BARRIER();

  // main loop: 16 K-steps; issue next stage FIRST, then compute, then explicit drain
#pragma unroll
  for (int tt = 0; tt < 16; ++tt) {
    if (tt < 15) {
      if (tt & 1) {
        STAGE((tt + 1) * 32, Af0, Bs0);
      } else {
        STAGE((tt + 1) * 32, Af1, Bs1);
      }
    }
    __builtin_amdgcn_sched_barrier(0);   // pin: stage issue stays before compute
    if (tt & 1) {
      COMPUTE(Af1, Bs1);
    } else {
      COMPUTE(Af0, Bs0);
    }
    DRAIN_BARRIER();
  }

  // ---- fused epilogue: LDS-coalesced gather of encW[dfn]+encW[dfa]+bias ----
  // Per wave: private 4KB region in Af0 (wave*4096). Chunk = mi (16 rows x 64 cols).
  // Load phase: lane j=lane>>2 (row), q=lane&3 (16-col quarter): coalesced f32x4 x4
  // per stream from L2-resident encW. Consume: lane picks its fragment values.
  // All intra-wave (disjoint regions); post-loop barrier already synced LDS reuse.
  float* myl = (float*)((char*)Af0 + wave * 4096);
#pragma unroll
  for (int mi = 0; mi < 4; ++mi) {
    {
      const int j = lane >> 2;
      const int q = lane & 3;
      const int row = m0 + wm * 64 + mi * 16 + j;
      const int colBase = n0 + wn * 64 + q * 16;
      const float* e1 = encW + (size_t)dfn[row] * D_MODEL + colBase;
      const float* e2 = encW + (size_t)dfa[row] * D_MODEL + colBase;
      const float* bb = bias + colBase;
      float* dstl = myl + j * 64 + q * 16;
#pragma unroll
      for (int v = 0; v < 4; ++v) {
        f32x4 a = *reinterpret_cast<const f32x4*>(e1 + v * 4);
        f32x4 b = *reinterpret_cast<const f32x4*>(e2 + v * 4);
        f32x4 c = *reinterpret_cast<const f32x4*>(bb + v * 4);
        *reinterpret_cast<f32x4*>(dstl + v * 4) = a + b + c;
      }
    }
    // cross-lane within wave: ds_write -> ds_read ordering via lgkmcnt (compiler) +
    // wave-lockstep issue order. Pin with a sched barrier for safety.
    __builtin_amdgcn_sched_barrier(0);
#pragma unroll
    for (int r = 0; r < 4; ++r) {
      const int row = m0 + wm * 64 + mi * 16 + lsl * 4 + r;
      const size_t ro = (size_t)row * D_MODEL;
#pragma unroll
      for (int ni = 0; ni < 4; ++ni) {
        const int col = n0 + wn * 64 + ni * 16 + l15;
        out[ro + col] = acc[mi][ni][r] + myl[(lsl * 4 + r) * 64 + ni * 16 + l15];
      }
    }
    __builtin_amdgcn_sched_barrier(0);   // reads done before next chunk overwrites
  }
#undef STAGE
#undef COMPUTE
#undef DRAIN_BARRIER
}

extern "C" void kernel_launch(void* const* d_in, const int* in_sizes, int n_in,
                              void* d_out, int out_size, void* d_ws, size_t ws_size,
                              hipStream_t stream) {
  const int* dfn = (const int*)d_in[0];
  const int* dfa = (const int*)d_in[1];
  const float* latent = (const float*)d_in[2];
  const float* enc = (const float*)d_in[3];
  const float* W = (const float*)d_in[4];
  const float* bias = (const float*)d_in[5];
  float* out = (float*)d_out;

  // workspace layout (4 MB total)
  char* ws = (char*)d_ws;
  short* WtT  = (short*)(ws);                       // 512KB  [512][512] bf16
  short* WbT  = (short*)(ws + 512 * 1024);          // 512KB  [512][512] bf16
  short* encb = (short*)(ws + 1024 * 1024);         // 1MB    [1024][512] bf16
  float* encW = (float*)(ws + 2 * 1024 * 1024);     // 2MB    [1024][512] f32

  hipLaunchKernelGGL(prep_w_kernel, dim3(8, 16), dim3(256), 0, stream, W, WtT, WbT);
  hipLaunchKernelGGL(prep_enc_kernel, dim3(512), dim3(256), 0, stream, enc, encb);
  hipLaunchKernelGGL(gemm_encw_kernel, dim3(4, 8), dim3(256), 0, stream, encb, WtT, encW);
  hipLaunchKernelGGL(gemm_main_kernel, dim3(2048), dim3(256), 0, stream,
                     latent, WbT, encW, dfn, dfa, bias, out);
}